// Round 1
// baseline (36.209 us; speedup 1.0000x reference)
//
#include <hip/hip_runtime.h>
#include <math.h>

namespace {
constexpr int kB = 32;
constexpr int kH = 38;
constexpr int kW = 38;
constexpr int kA = 5;
constexpr int kC = 80;
constexpr int kT = 60;
constexpr int kHW = kH * kW;                    // 1444
constexpr int kCellsPerB = kHW * kA;            // 7220
constexpr int kNSeg = kB * kCellsPerB;          // 231040
constexpr int kChan = 5 + kC;                   // 85
constexpr int kMainBlocks = (kCellsPerB + 255) / 256;  // 29
constexpr int kNPart = kMainBlocks * kB;        // 928
constexpr float kThresh = 0.6f;
constexpr int kPriorIter = 12800;
}

// ---------------------------------------------------------------------------
// Kernel 0: zero the packed-winner array (ws is poisoned / stale each call).
// ---------------------------------------------------------------------------
__global__ void yolo_zero_kernel(unsigned long long* __restrict__ packed) {
    int i = blockIdx.x * blockDim.x + threadIdx.x;
    if (i < kNSeg) packed[i] = 0ULL;
}

// ---------------------------------------------------------------------------
// Kernel 1: per-truth best-anchor selection + winner election via atomicMax.
// packed = (iou_bits << 32) | (0xFFFFFFFF - order); positive-float bits are
// monotone, so max(packed) == (max iou, then min order) == reference's
// segment_max + segment_min-first tiebreak.
// ---------------------------------------------------------------------------
__global__ void yolo_truth_kernel(const float* __restrict__ truths,
                                  const float* __restrict__ anchors,
                                  unsigned long long* __restrict__ packed) {
    int i = blockIdx.x * blockDim.x + threadIdx.x;  // i = b*kT + t  (== order)
    if (i >= kB * kT) return;
    int b = i / kT;
    const float* tr = truths + (size_t)i * 5;
    float x1 = tr[0], y1 = tr[1], x2 = tr[2], y2 = tr[3];
    float tcx = (x1 + x2) * 0.5f, tcy = (y1 + y2) * 0.5f;
    float tw = x2 - x1, th = y2 - y1;
    float tdx = tcx * (float)kW, tdy = tcy * (float)kH;
    int gxi = (int)(ceilf(tdx) - 1.0f);
    int gyi = (int)(ceilf(tdy) - 1.0f);
    gxi = min(max(gxi, 0), kW - 1);
    gyi = min(max(gyi, 0), kH - 1);
    float tarea = tw * th;
    float best = -1.0f;
    int ba = 0;
    for (int a = 0; a < kA; ++a) {
        float aw = anchors[2 * a], ah = anchors[2 * a + 1];
        float iw = fminf(tw, aw), ih = fminf(th, ah);
        float inter = iw * ih;
        float uni = fmaxf(tarea + aw * ah - inter, 1e-12f);
        float iou = inter / uni;
        if (iou > best) { best = iou; ba = a; }   // strict > keeps first (argmax)
    }
    int pos = gyi * kW + gxi;
    int key = (b * kHW + pos) * kA + ba;
    unsigned long long pk =
        ((unsigned long long)__float_as_uint(best) << 32) |
        (unsigned long long)(0xFFFFFFFFu - (unsigned int)i);
    atomicMax(&packed[key], pk);
}

// ---------------------------------------------------------------------------
// Kernel 2: per-cell loss. grid = (29, B); each thread = one (hw, a) cell of
// batch blockIdx.y. Truths staged in LDS. Class channels (80/85 of the input)
// are read ONLY at responsible cells (<= 1920 total).
// ---------------------------------------------------------------------------
__global__ __launch_bounds__(256) void yolo_main_kernel(
    const float* __restrict__ output,
    const float* __restrict__ truths,
    const float* __restrict__ anchors,
    const int* __restrict__ iter_p,
    const unsigned long long* __restrict__ packed,
    float* __restrict__ partial) {
    const int b = blockIdx.y;
    const int idx = blockIdx.x * blockDim.x + threadIdx.x;  // cell within batch

    __shared__ float st[kT][6];     // x1,y1,x2,y2,cls,area
    __shared__ float sanch[2 * kA];
    if (threadIdx.x < 2 * kA) sanch[threadIdx.x] = anchors[threadIdx.x];
    if (threadIdx.x < kT) {
        const float* tr = truths + ((size_t)b * kT + threadIdx.x) * 5;
        float x1 = tr[0], y1 = tr[1], x2 = tr[2], y2 = tr[3], cls = tr[4];
        st[threadIdx.x][0] = x1;
        st[threadIdx.x][1] = y1;
        st[threadIdx.x][2] = x2;
        st[threadIdx.x][3] = y2;
        st[threadIdx.x][4] = cls;
        st[threadIdx.x][5] = (x2 - x1) * (y2 - y1);
    }
    __syncthreads();

    const bool priorOn = (*iter_p < kPriorIter);
    float contrib = 0.0f;

    if (idx < kCellsPerB) {
        const int a = idx % kA;
        const int hw = idx / kA;
        const int gx = hw % kW;
        const int gy = hw / kW;
        const float* p = output + ((size_t)b * kHW + hw) * kChan + (size_t)a * kChan;
        const float t0 = p[0], t1 = p[1], t2 = p[2], t3 = p[3], t4 = p[4];
        const float aw = sanch[2 * a], ah = sanch[2 * a + 1];

        const float sx = 1.0f / (1.0f + expf(-t0));
        const float sy = 1.0f / (1.0f + expf(-t1));
        const float cx = (sx + (float)gx) / (float)kW;
        const float cy = (sy + (float)gy) / (float)kH;
        const float pw = expf(t2) * aw;
        const float ph = expf(t3) * ah;
        const float px1 = cx - pw * 0.5f, px2 = cx + pw * 0.5f;
        const float py1 = cy - ph * 0.5f, py2 = cy + ph * 0.5f;
        const float parea = (px2 - px1) * (py2 - py1);

        // noobj candidate: max IoU(pred box, any truth) < THRESH
        float mx = 0.0f;
        for (int t = 0; t < kT; ++t) {
            float xm = fmaxf(px1, st[t][0]);
            float xM = fminf(px2, st[t][2]);
            float ym = fmaxf(py1, st[t][1]);
            float yM = fminf(py2, st[t][3]);
            float inter = fmaxf(xM - xm, 0.0f) * fmaxf(yM - ym, 0.0f);
            float uni = fmaxf(parea + st[t][5] - inter, 1e-12f);
            mx = fmaxf(mx, inter / uni);
        }
        const bool noobj = (mx < kThresh);

        if (priorOn) {
            float dw = pw - aw, dh = ph - ah;
            contrib += dw * dw + dh * dh;   // PRIOR_RATE = 1
        }

        const unsigned long long pk = packed[(size_t)b * kCellsPerB + idx];
        if (pk != 0ULL) {
            // responsible cell: decode winning truth, rebuild targets
            const unsigned int order = 0xFFFFFFFFu - (unsigned int)(pk & 0xFFFFFFFFULL);
            const int t = (int)(order % kT);
            const float x1 = st[t][0], y1 = st[t][1], x2 = st[t][2], y2 = st[t][3];
            const float tw = x2 - x1, th = y2 - y1;
            const float tdx = (x1 + x2) * 0.5f * (float)kW;
            const float tdy = (y1 + y2) * 0.5f * (float)kH;
            const float fx = tdx - (ceilf(tdx) - 1.0f);
            const float fy = tdy - (ceilf(tdy) - 1.0f);
            const float ddx = -logf(1.0f / fx - 1.0f);
            const float ddy = -logf(1.0f / fy - 1.0f);
            const float wh0 = logf(tw) / aw;
            const float wh1 = logf(th) / ah;
            const float iou = __uint_as_float((unsigned int)(pk >> 32));
            const float fix2 = 2.0f - tw * th;  // fix^2 (always > 1.8)
            const float d0 = t0 - ddx, d1 = t1 - ddy, d2 = t2 - wh0, d3 = t3 - wh1;
            contrib += fix2 * (d0 * d0 + d1 * d1 + d2 * d2 + d3 * d3);  // COORD
            const float dob = t4 - iou;
            contrib += 5.0f * dob * dob;                                 // OBJECT
            const int cls = (int)st[t][4];
            float csum = 0.0f;
            for (int c = 0; c < kC; ++c) {
                float pc = p[5 + c];
                float tgt = (c == cls) ? 1.0f : 0.0f;
                float d = pc - tgt;
                csum += d * d;
            }
            contrib += csum;                                             // CLASS
        } else if (noobj) {
            contrib += t4 * t4;                                          // NOOBJ
        }
    }

    // deterministic block reduction: wave shuffle + LDS across the 4 waves
    for (int off = 32; off > 0; off >>= 1) contrib += __shfl_down(contrib, off);
    __shared__ float wsum[4];
    const int lane = threadIdx.x & 63;
    const int wid = threadIdx.x >> 6;
    if (lane == 0) wsum[wid] = contrib;
    __syncthreads();
    if (threadIdx.x == 0) {
        partial[blockIdx.y * gridDim.x + blockIdx.x] =
            wsum[0] + wsum[1] + wsum[2] + wsum[3];
    }
}

// ---------------------------------------------------------------------------
// Kernel 3: deterministic final reduction of the 928 block partials.
// ---------------------------------------------------------------------------
__global__ void yolo_reduce_kernel(const float* __restrict__ partial,
                                   float* __restrict__ out) {
    __shared__ float s[256];
    float v = 0.0f;
    for (int i = threadIdx.x; i < kNPart; i += 256) v += partial[i];
    s[threadIdx.x] = v;
    __syncthreads();
    for (int off = 128; off > 0; off >>= 1) {
        if (threadIdx.x < off) s[threadIdx.x] += s[threadIdx.x + off];
        __syncthreads();
    }
    if (threadIdx.x == 0) out[0] = s[0] * (1.0f / (float)kB);
}

extern "C" void kernel_launch(void* const* d_in, const int* in_sizes, int n_in,
                              void* d_out, int out_size, void* d_ws, size_t ws_size,
                              hipStream_t stream) {
    const float* output  = (const float*)d_in[0];
    const float* truths  = (const float*)d_in[1];
    const float* anchors = (const float*)d_in[2];
    const int*   iter_p  = (const int*)d_in[3];
    float* out = (float*)d_out;

    unsigned long long* packed = (unsigned long long*)d_ws;
    float* partial = (float*)((char*)d_ws + (size_t)kNSeg * sizeof(unsigned long long));

    hipLaunchKernelGGL(yolo_zero_kernel, dim3((kNSeg + 255) / 256), dim3(256), 0,
                       stream, packed);
    hipLaunchKernelGGL(yolo_truth_kernel, dim3((kB * kT + 255) / 256), dim3(256), 0,
                       stream, truths, anchors, packed);
    hipLaunchKernelGGL(yolo_main_kernel, dim3(kMainBlocks, kB), dim3(256), 0,
                       stream, output, truths, anchors, iter_p, packed, partial);
    hipLaunchKernelGGL(yolo_reduce_kernel, dim3(1), dim3(256), 0,
                       stream, partial, out);
}